// Round 10
// baseline (107.036 us; speedup 1.0000x reference)
//
#include <hip/hip_runtime.h>

// ROIPatchExtractor: B=32, C=3, H=W=448, 2x2 patches -> N=128 samples.
// Composed separable bilinear (patch->448 upsample, then ROI crop+resize):
// each output row/col = weighted 3-tap sum of <=3 consecutive patch rows/cols.
//
// r10: ALL-REGISTER design. r2-r9 post-mortems: hrow LDS is per-thread
// scratch (thread tid writes hrow[k][tid], only tid reads it) -> the ~42
// DS ops/thread + 3 wave-rendezvous were the residual. r6's register attempt
// failed on serial rolling gathers (no MLP); here we batch-issue all 24
// gathers per channel (8 padded rows x 3 taps, unconditional) into
// registers, fold to h[0..7], and do the vertical pass from registers.
// The window index k0 = ra - pr_min is block-uniform and <= 4, selected by
// a readfirstlane-scalarized switch (static register indexing, uniform
// s_cbranch). Row padding (min(pr_min+k,223)) makes k0+1/k0+2 exact under
// the 223-clamp. Only LDS: 8-entry rowE table + 1 soft barrier; channel-0
// gathers issue before the barrier.

#define IMG 448
#define PATCH 224
#define ROWS 8     // output rows per block; grid.x = 448/8 = 56
#define NPR 8      // padded patch-row window (k0<=4, +3 taps -> 7; pad to 8)

#define SOFT_BARRIER()                                          \
    do {                                                        \
        asm volatile("s_waitcnt lgkmcnt(0)" ::: "memory");      \
        __builtin_amdgcn_s_barrier();                           \
        asm volatile("" ::: "memory");                          \
    } while (0)

__device__ inline float4 make_entry(int t, int crop, int off) {
    // stage 2: output coord t -> up-image coords u0,u1 with weight wy
    float cf = (float)crop;
    float s = ((float)t + 0.5f) * cf / 448.0f - 0.5f;
    s = fminf(fmaxf(s, 0.0f), cf - 1.0f);
    int i0 = (int)s;                 // s >= 0, trunc == floor
    int i1 = min(i0 + 1, crop - 1);
    float wy = s - (float)i0;
    int u0 = off + i0;
    int u1 = off + i1;
    // stage 1: up coord u -> patch coord: s1 = 0.5*u - 0.25, clamp [0,223]
    float t0 = fminf(fmaxf(0.5f * (float)u0 - 0.25f, 0.0f), 223.0f);
    int a0 = (int)t0;
    int a1 = min(a0 + 1, 223);
    float f0 = t0 - (float)a0;
    float t1 = fminf(fmaxf(0.5f * (float)u1 - 0.25f, 0.0f), 223.0f);
    int b0 = (int)t1;
    int b1 = min(b0 + 1, 223);
    float f1 = t1 - (float)b0;
    // fold 4 taps into 3 slots relative to a0 (footprint <= a0+2)
    float g0 = (1.0f - wy) * (1.0f - f0);
    float g1 = (1.0f - wy) * f0;
    float g2 = wy * (1.0f - f1);
    float g3 = wy * f1;
    float w0 = g0, w1 = 0.0f, w2 = 0.0f;
    if (a1 == a0) w0 += g1; else w1 += g1;
    if (b0 == a0) w0 += g2; else w1 += g2;
    int ob1 = b1 - a0;
    if (ob1 == 0) w0 += g3; else if (ob1 == 1) w1 += g3; else w2 += g3;
    float4 e;
    e.x = w0; e.y = w1; e.z = w2;
    e.w = __int_as_float(a0);        // patch-local base index [0,223]
    return e;
}

__global__ __launch_bounds__(448)
void roi_patch_kernel(const float* __restrict__ x,
                      const int* __restrict__ tops,
                      const int* __restrict__ lefts,
                      const int* __restrict__ crop_hs,
                      const int* __restrict__ crop_ws,
                      float* __restrict__ out,
                      int out_size) {
    __shared__ float4 rowE[ROWS];

    const int n   = blockIdx.y;
    const int y0  = blockIdx.x * ROWS;
    const int tid = threadIdx.x;
    const int b   = n >> 2;
    const int gi  = (n >> 1) & 1;
    const int gj  = n & 1;

    const int ch = crop_hs[n], cw = crop_ws[n];
    const int tp = tops[n],    lf = lefts[n];

    // per-thread column entry (col = tid) -- registers
    const float4 ce = make_entry(tid, cw, lf);
    const int ca = __float_as_int(ce.w);
    const int cb = gj * PATCH;
    const int c0 = cb + ca;
    const int c1 = cb + min(ca + 1, 223);
    const int c2 = cb + min(ca + 2, 223);

    if (tid < ROWS) rowE[tid] = make_entry(y0 + tid, ch, tp);

    // patch_indices tail (float values; harness reads flat buffer as f32)
    if (blockIdx.x == 0 && n == 0 && tid < 128) {
        out[(size_t)out_size - 128 + tid] = (float)(tid & 3);
    }

    // block-uniform window start (computed per-thread; no LDS dep)
    const int pr_min = __float_as_int(make_entry(y0, ch, tp).w);
    const int pr_min_s = __builtin_amdgcn_readfirstlane(pr_min);

    // padded row offsets (floats) relative to xb: row k -> min(pr_min+k,223)
    int roff[NPR];
    #pragma unroll
    for (int k = 0; k < NPR; ++k)
        roff[k] = (min(pr_min + k, 223) - pr_min) * IMG;

    const float* xb = x + (size_t)b * 3 * IMG * IMG + (size_t)(gi * PATCH + pr_min) * IMG;
    float* ob = out + (size_t)n * 3 * IMG * IMG + (size_t)y0 * IMG + tid;

    float v0[NPR], v1[NPR], v2[NPR], h[NPR];

#define GATHER(CH)                                                        \
    {                                                                     \
        const float* xc = xb + (size_t)(CH) * IMG * IMG;                  \
        _Pragma("unroll")                                                 \
        for (int k = 0; k < NPR; ++k) {                                   \
            const float* xr = xc + roff[k];                               \
            v0[k] = xr[c0]; v1[k] = xr[c1]; v2[k] = xr[c2];               \
        }                                                                 \
    }

#define HFOLD()                                                           \
    {                                                                     \
        _Pragma("unroll")                                                 \
        for (int k = 0; k < NPR; ++k)                                     \
            h[k] = ce.x * v0[k] + ce.y * v1[k] + ce.z * v2[k];            \
    }

    // vertical pass: block-uniform k0 (<=4), scalarized switch -> static regs
#define VPASS(CH)                                                         \
    {                                                                     \
        float* orow = ob + (size_t)(CH) * IMG * IMG;                      \
        _Pragma("unroll")                                                 \
        for (int r = 0; r < ROWS; ++r) {                                  \
            const float4 re = rowE[r];                                    \
            const int k0 = __builtin_amdgcn_readfirstlane(                \
                               __float_as_int(re.w)) - pr_min_s;          \
            float v;                                                      \
            switch (k0) {                                                 \
            case 0:  v = re.x * h[0] + re.y * h[1] + re.z * h[2]; break;  \
            case 1:  v = re.x * h[1] + re.y * h[2] + re.z * h[3]; break;  \
            case 2:  v = re.x * h[2] + re.y * h[3] + re.z * h[4]; break;  \
            case 3:  v = re.x * h[3] + re.y * h[4] + re.z * h[5]; break;  \
            case 4:  v = re.x * h[4] + re.y * h[5] + re.z * h[6]; break;  \
            default: v = re.x * h[5] + re.y * h[6] + re.z * h[7]; break;  \
            }                                                             \
            *orow = v;                                                    \
            orow += IMG;                                                  \
        }                                                                 \
    }

    // channel 0 gathers in flight across the rowE barrier
    GATHER(0);
    SOFT_BARRIER();          // publishes rowE; does not drain gathers

    HFOLD();
    VPASS(0);

    GATHER(1);
    HFOLD();
    VPASS(1);

    GATHER(2);
    HFOLD();
    VPASS(2);

#undef GATHER
#undef HFOLD
#undef VPASS
}

extern "C" void kernel_launch(void* const* d_in, const int* in_sizes, int n_in,
                              void* d_out, int out_size, void* d_ws, size_t ws_size,
                              hipStream_t stream) {
    const float* x        = (const float*)d_in[0];
    const int*   tops     = (const int*)d_in[1];
    const int*   lefts    = (const int*)d_in[2];
    const int*   crop_hs  = (const int*)d_in[3];
    const int*   crop_ws  = (const int*)d_in[4];
    float*       out      = (float*)d_out;

    dim3 grid(IMG / ROWS, 128);   // 56 x 128 blocks
    dim3 block(IMG);              // 448 threads = 7 waves
    roi_patch_kernel<<<grid, block, 0, stream>>>(x, tops, lefts, crop_hs, crop_ws,
                                                 out, out_size);
}